// Round 1
// baseline (829.947 us; speedup 1.0000x reference)
//
#include <hip/hip_runtime.h>
#include <hip/hip_bf16.h>

#define N_NODES 50000
#define NE      800000
#define DIN     64     // D
#define H1      128    // H
#define H2      64     // H/2

// ---------------- degree kernels ----------------

__global__ void zero_i32(int* __restrict__ p, int n) {
    int i = blockIdx.x * 256 + threadIdx.x;
    if (i < n) p[i] = 0;
}

__global__ void degree_hist(const int* __restrict__ src, const int* __restrict__ dst,
                            int* __restrict__ outd, int* __restrict__ ind) {
    int i = blockIdx.x * 256 + threadIdx.x;
    if (i < NE) {
        atomicAdd(outd + src[i], 1);
        atomicAdd(ind + dst[i], 1);
    }
}

// ---------------- main fused edge-MLP kernel ----------------
// One thread = one edge. Weight loads are wave-uniform -> scalar loads,
// amortized across 64 edges/wave. h1 (post-LN) staged per-thread in LDS as
// bf16 [k][tid] so the layer-2 k-loop can be dynamic (no runtime-indexed
// register arrays -> no scratch).

__global__ __launch_bounds__(128) void edge_mlp(
    const float* __restrict__ emb,
    const int*   __restrict__ src, const int* __restrict__ dst,
    const float* __restrict__ noise,
    const float* __restrict__ W1, const float* __restrict__ b1,
    const float* __restrict__ g1, const float* __restrict__ bt1,
    const float* __restrict__ W2, const float* __restrict__ b2,
    const float* __restrict__ g2, const float* __restrict__ bt2,
    const float* __restrict__ W3, const float* __restrict__ b3,
    const int*   __restrict__ outd, const int* __restrict__ ind,
    float* __restrict__ out)
{
    __shared__ __hip_bfloat16 hs[H1][128];   // [k][tid], 32 KB, conflict-free

    const int t = threadIdx.x;
    const int e = blockIdx.x * 128 + t;      // NE % 128 == 0

    const int sn = src[e];
    const int dn = dst[e];

    // ---- layer 1: h1 = x @ W1 + b1, x = [emb[sn], emb[dn]] ----
    float h1[H1];
#pragma unroll
    for (int j = 0; j < H1; ++j) h1[j] = b1[j];

    {
        const float4* xr = (const float4*)(emb + (size_t)sn * DIN);
#pragma unroll 1
        for (int kb = 0; kb < 8; ++kb) {      // k = kb*8 .. kb*8+7 (src half)
            float4 a0 = xr[2 * kb];
            float4 a1 = xr[2 * kb + 1];
            float xk[8] = {a0.x, a0.y, a0.z, a0.w, a1.x, a1.y, a1.z, a1.w};
            const float* wr = W1 + (size_t)(kb * 8) * H1;
#pragma unroll
            for (int i = 0; i < 8; ++i) {
#pragma unroll
                for (int j = 0; j < H1; ++j)
                    h1[j] = fmaf(xk[i], wr[i * H1 + j], h1[j]);
            }
        }
    }
    {
        const float4* xr = (const float4*)(emb + (size_t)dn * DIN);
#pragma unroll 1
        for (int kb = 0; kb < 8; ++kb) {      // k = 64 + kb*8 ... (dst half)
            float4 a0 = xr[2 * kb];
            float4 a1 = xr[2 * kb + 1];
            float xk[8] = {a0.x, a0.y, a0.z, a0.w, a1.x, a1.y, a1.z, a1.w};
            const float* wr = W1 + (size_t)(DIN + kb * 8) * H1;
#pragma unroll
            for (int i = 0; i < 8; ++i) {
#pragma unroll
                for (int j = 0; j < H1; ++j)
                    h1[j] = fmaf(xk[i], wr[i * H1 + j], h1[j]);
            }
        }
    }

    // ---- LN1 + relu -> LDS (bf16) ----
    {
        float mu = 0.f;
#pragma unroll
        for (int j = 0; j < H1; ++j) mu += h1[j];
        mu *= (1.0f / H1);
        float var = 0.f;
#pragma unroll
        for (int j = 0; j < H1; ++j) { float d = h1[j] - mu; var = fmaf(d, d, var); }
        float rs = rsqrtf(var * (1.0f / H1) + 1e-5f);
#pragma unroll
        for (int j = 0; j < H1; ++j) {
            float y = fmaf((h1[j] - mu) * rs, g1[j], bt1[j]);
            y = fmaxf(y, 0.0f);
            hs[j][t] = __float2bfloat16(y);
        }
    }
    // no barrier: each thread reads only its own column

    // ---- layer 2: h2 = h1n @ W2 + b2 ----
    float h2[H2];
#pragma unroll
    for (int j = 0; j < H2; ++j) h2[j] = b2[j];

#pragma unroll 4
    for (int k = 0; k < H1; ++k) {
        float hk = __bfloat162float(hs[k][t]);
        const float* wr = W2 + (size_t)k * H2;
#pragma unroll
        for (int j = 0; j < H2; ++j)
            h2[j] = fmaf(hk, wr[j], h2[j]);
    }

    // ---- LN2 + relu + dot(W3) ----
    float mu2 = 0.f;
#pragma unroll
    for (int j = 0; j < H2; ++j) mu2 += h2[j];
    mu2 *= (1.0f / H2);
    float var2 = 0.f;
#pragma unroll
    for (int j = 0; j < H2; ++j) { float d = h2[j] - mu2; var2 = fmaf(d, d, var2); }
    float rs2 = rsqrtf(var2 * (1.0f / H2) + 1e-5f);

    float logit = b3[0];
#pragma unroll
    for (int j = 0; j < H2; ++j) {
        float y = fmaf((h2[j] - mu2) * rs2, g2[j], bt2[j]);
        y = fmaxf(y, 0.0f);
        logit = fmaf(y, W3[j], logit);
    }

    // ---- concrete gate + degree norm ----
    float nz = noise[e];
    float z = __logf(nz) - log1pf(-nz) + logit;
    float gate = 1.0f / (1.0f + __expf(-z));

    int od = outd[sn]; od = od < 1 ? 1 : od;
    int id = ind[dn];  id = id < 1 ? 1 : id;
    float norm = rsqrtf((float)od) * rsqrtf((float)id);

    out[e] = gate * norm;
}

// ---------------- launch ----------------

extern "C" void kernel_launch(void* const* d_in, const int* in_sizes, int n_in,
                              void* d_out, int out_size, void* d_ws, size_t ws_size,
                              hipStream_t stream) {
    const float* emb   = (const float*)d_in[0];
    const int*   src   = (const int*)  d_in[1];
    const int*   dst   = (const int*)  d_in[2];
    const float* noise = (const float*)d_in[3];
    const float* W1  = (const float*)d_in[4];
    const float* b1  = (const float*)d_in[5];
    const float* g1  = (const float*)d_in[6];
    const float* bt1 = (const float*)d_in[7];
    const float* W2  = (const float*)d_in[8];
    const float* b2  = (const float*)d_in[9];
    const float* g2  = (const float*)d_in[10];
    const float* bt2 = (const float*)d_in[11];
    const float* W3  = (const float*)d_in[12];
    const float* b3  = (const float*)d_in[13];

    int* outd = (int*)d_ws;
    int* ind  = outd + N_NODES;

    zero_i32<<<(2 * N_NODES + 255) / 256, 256, 0, stream>>>(outd, 2 * N_NODES);
    degree_hist<<<(NE + 255) / 256, 256, 0, stream>>>(src, dst, outd, ind);
    edge_mlp<<<NE / 128, 128, 0, stream>>>(emb, src, dst, noise,
                                           W1, b1, g1, bt1,
                                           W2, b2, g2, bt2,
                                           W3, b3, outd, ind,
                                           (float*)d_out);
}

// Round 2
// 206.482 us; speedup vs baseline: 4.0195x; 4.0195x over previous
//
#include <hip/hip_runtime.h>
#include <hip/hip_bf16.h>

#define N_NODES 50000
#define NE      800000
#define NTILES  (NE / 16)

typedef __attribute__((ext_vector_type(8))) short bf16x8;
typedef __attribute__((ext_vector_type(4))) float f32x4;

static __device__ __forceinline__ short f2bf(float x) {
    union { float f; unsigned u; } v; v.f = x;
    unsigned r = (v.u + 0x7fffu + ((v.u >> 16) & 1u)) >> 16;  // RNE
    return (short)r;
}

// ---------------- degree kernels ----------------

__global__ void zero_i32(int* __restrict__ p, int n) {
    int i = blockIdx.x * 256 + threadIdx.x;
    if (i < n) p[i] = 0;
}

__global__ void degree_hist(const int* __restrict__ src, const int* __restrict__ dst,
                            int* __restrict__ outd, int* __restrict__ ind) {
    int i = blockIdx.x * 256 + threadIdx.x;
    if (i < NE) {
        atomicAdd(outd + src[i], 1);
        atomicAdd(ind + dst[i], 1);
    }
}

// ---------------- MFMA edge-MLP ----------------
// Per wave-iteration: 16 edges. mfma_f32_16x16x32_bf16.
// A layout: lane l holds A[l&15][(l>>4)*8 + j], j=0..7
// B layout: lane l holds B[(l>>4)*8 + j][l&15]
// C layout: lane l holds C[(l>>4)*4 + reg][l&15]   (m89-verified)
// LDS: W1 frags 16384 shorts | W2 frags 8192 | per-wave H tile 4*2048 = 64 KB

__global__ __launch_bounds__(256, 2) void edge_mlp_mfma(
    const float* __restrict__ emb,
    const int*   __restrict__ src, const int* __restrict__ dst,
    const float* __restrict__ noise,
    const float* __restrict__ W1, const float* __restrict__ b1,
    const float* __restrict__ g1, const float* __restrict__ bt1,
    const float* __restrict__ W2, const float* __restrict__ b2,
    const float* __restrict__ g2, const float* __restrict__ bt2,
    const float* __restrict__ W3, const float* __restrict__ b3,
    const int*   __restrict__ outd, const int* __restrict__ ind,
    float* __restrict__ out)
{
    __shared__ short lds[32768];  // 64 KB

    const int tid = threadIdx.x;
    const int wid = tid >> 6;      // wave 0..3
    const int l   = tid & 63;
    const int g   = l >> 4;        // k-group 0..3
    const int c   = l & 15;        // column / edge-in-tile

    // ---- stage W1 fragments (B-layout order: [(ks*8+t)][lane][8]) ----
    for (int i = tid; i < 16384; i += 256) {
        int j = i & 7, lane = (i >> 3) & 63, p = i >> 9;
        int ks = p >> 3, t = p & 7;
        int row = ks * 32 + (lane >> 4) * 8 + j;   // k index 0..127
        int col = t * 16 + (lane & 15);            // out feature 0..127
        lds[i] = f2bf(W1[row * 128 + col]);
    }
    // ---- stage W2 fragments ([(ks*4+t)][lane][8]) ----
    for (int i = tid; i < 8192; i += 256) {
        int j = i & 7, lane = (i >> 3) & 63, p = i >> 9;
        int ks = p >> 2, t = p & 3;
        int row = ks * 32 + (lane >> 4) * 8 + j;   // k 0..127
        int col = t * 16 + (lane & 15);            // out feature 0..63
        lds[16384 + i] = f2bf(W2[row * 64 + col]);
    }
    __syncthreads();

    short* Hl = lds + 24576 + wid * 2048;  // per-wave 16x128 bf16, swizzled

    // per-lane constants
    float b1v[8], g1v[8], t1v[8];
#pragma unroll
    for (int t = 0; t < 8; ++t) { int f = t * 16 + c; b1v[t] = b1[f]; g1v[t] = g1[f]; t1v[t] = bt1[f]; }
    float b2v[4], g2v[4], t2v[4], w3v[4];
#pragma unroll
    for (int t = 0; t < 4; ++t) { int f = t * 16 + c; b2v[t] = b2[f]; g2v[t] = g2[f]; t2v[t] = bt2[f]; w3v[t] = W3[f]; }
    const float b3v = b3[0];

    const int gw = blockIdx.x * 4 + wid;
    const int nw = gridDim.x * 4;

    for (int tile = gw; tile < NTILES; tile += nw) {
        const int e0 = tile * 16 + c;
        const int sn = src[e0], dn = dst[e0];

        // ---- gather layer-1 A fragments ----
        const f32x4* sp = (const f32x4*)(emb + (size_t)sn * 64);
        const f32x4* dp = (const f32x4*)(emb + (size_t)dn * 64);
        f32x4 u[8];
        u[0] = sp[2 * g]; u[1] = sp[2 * g + 1];     // k = g*8..      (src)
        u[2] = sp[8 + 2 * g]; u[3] = sp[8 + 2 * g + 1]; // k = 32+g*8 (src)
        u[4] = dp[2 * g]; u[5] = dp[2 * g + 1];     // k = 64+g*8     (dst)
        u[6] = dp[8 + 2 * g]; u[7] = dp[8 + 2 * g + 1]; // k = 96+g*8 (dst)

        bf16x8 a1[4];
#pragma unroll
        for (int ks = 0; ks < 4; ++ks) {
            f32x4 x0 = u[2 * ks], x1 = u[2 * ks + 1];
            bf16x8 a;
            a[0] = f2bf(x0[0]); a[1] = f2bf(x0[1]); a[2] = f2bf(x0[2]); a[3] = f2bf(x0[3]);
            a[4] = f2bf(x1[0]); a[5] = f2bf(x1[1]); a[6] = f2bf(x1[2]); a[7] = f2bf(x1[3]);
            a1[ks] = a;
        }

        // ---- layer 1 MFMAs ----
        f32x4 acc1[8];
#pragma unroll
        for (int t = 0; t < 8; ++t) { f32x4 z = {b1v[t], b1v[t], b1v[t], b1v[t]}; acc1[t] = z; }
#pragma unroll
        for (int ks = 0; ks < 4; ++ks) {
#pragma unroll
            for (int t = 0; t < 8; ++t) {
                bf16x8 b = *(const bf16x8*)(lds + (ks * 8 + t) * 512 + l * 8);
                acc1[t] = __builtin_amdgcn_mfma_f32_16x16x32_bf16(a1[ks], b, acc1[t], 0, 0, 0);
            }
        }

        // ---- LN1 (reduce across 16 lanes per edge-row) + relu -> H (LDS) ----
        float mean[4], rstd[4];
#pragma unroll
        for (int r = 0; r < 4; ++r) {
            float s = acc1[0][r];
#pragma unroll
            for (int t = 1; t < 8; ++t) s += acc1[t][r];
            s += __shfl_xor(s, 1); s += __shfl_xor(s, 2);
            s += __shfl_xor(s, 4); s += __shfl_xor(s, 8);
            float m = s * (1.0f / 128.0f);
            float q = 0.f;
#pragma unroll
            for (int t = 0; t < 8; ++t) { float d = acc1[t][r] - m; q = fmaf(d, d, q); }
            q += __shfl_xor(q, 1); q += __shfl_xor(q, 2);
            q += __shfl_xor(q, 4); q += __shfl_xor(q, 8);
            mean[r] = m; rstd[r] = rsqrtf(q * (1.0f / 128.0f) + 1e-5f);
        }
#pragma unroll
        for (int r = 0; r < 4; ++r) {
            int rw = g * 4 + r;
            int swz = (rw & 7) << 3;
#pragma unroll
            for (int t = 0; t < 8; ++t) {
                float y = fmaf((acc1[t][r] - mean[r]) * rstd[r], g1v[t], t1v[t]);
                y = fmaxf(y, 0.f);
                Hl[rw * 128 + ((t * 16 + c) ^ swz)] = f2bf(y);
            }
        }

        // ---- layer 2: A frags from swizzled H ----
        bf16x8 a2[4];
        const int swzr = (c & 7) << 3;
#pragma unroll
        for (int ks = 0; ks < 4; ++ks)
            a2[ks] = *(const bf16x8*)(Hl + c * 128 + ((ks * 32 + g * 8) ^ swzr));

        f32x4 acc2[4];
#pragma unroll
        for (int t = 0; t < 4; ++t) { f32x4 z = {b2v[t], b2v[t], b2v[t], b2v[t]}; acc2[t] = z; }
#pragma unroll
        for (int ks = 0; ks < 4; ++ks) {
#pragma unroll
            for (int t = 0; t < 4; ++t) {
                bf16x8 b = *(const bf16x8*)(lds + 16384 + (ks * 4 + t) * 512 + l * 8);
                acc2[t] = __builtin_amdgcn_mfma_f32_16x16x32_bf16(a2[ks], b, acc2[t], 0, 0, 0);
            }
        }

        // ---- LN2 + relu + dot(W3) ----
        float logit[4];
#pragma unroll
        for (int r = 0; r < 4; ++r) {
            float s = acc2[0][r] + acc2[1][r] + acc2[2][r] + acc2[3][r];
            s += __shfl_xor(s, 1); s += __shfl_xor(s, 2);
            s += __shfl_xor(s, 4); s += __shfl_xor(s, 8);
            float m = s * (1.0f / 64.0f);
            float q = 0.f;
#pragma unroll
            for (int t = 0; t < 4; ++t) { float d = acc2[t][r] - m; q = fmaf(d, d, q); }
            q += __shfl_xor(q, 1); q += __shfl_xor(q, 2);
            q += __shfl_xor(q, 4); q += __shfl_xor(q, 8);
            float rs = rsqrtf(q * (1.0f / 64.0f) + 1e-5f);
            float p = 0.f;
#pragma unroll
            for (int t = 0; t < 4; ++t) {
                float y = fmaf((acc2[t][r] - m) * rs, g2v[t], t2v[t]);
                y = fmaxf(y, 0.f);
                p = fmaf(y, w3v[t], p);
            }
            p += __shfl_xor(p, 1); p += __shfl_xor(p, 2);
            p += __shfl_xor(p, 4); p += __shfl_xor(p, 8);
            logit[r] = p + b3v;
        }

        // ---- gate + degree norm (16 active lanes) ----
        if (c < 4) {
            int e = tile * 16 + g * 4 + c;
            float lg = (c == 0) ? logit[0] : (c == 1) ? logit[1] : (c == 2) ? logit[2] : logit[3];
            float nz = noise[e];
            float z = __logf(nz) - log1pf(-nz) + lg;
            float gate = 1.0f / (1.0f + __expf(-z));
            int od = outd[src[e]]; if (od < 1) od = 1;
            int idg = ind[dst[e]]; if (idg < 1) idg = 1;
            out[e] = gate * (rsqrtf((float)od) * rsqrtf((float)idg));
        }
    }
}

// ---------------- launch ----------------

extern "C" void kernel_launch(void* const* d_in, const int* in_sizes, int n_in,
                              void* d_out, int out_size, void* d_ws, size_t ws_size,
                              hipStream_t stream) {
    const float* emb   = (const float*)d_in[0];
    const int*   src   = (const int*)  d_in[1];
    const int*   dst   = (const int*)  d_in[2];
    const float* noise = (const float*)d_in[3];
    const float* W1  = (const float*)d_in[4];
    const float* b1  = (const float*)d_in[5];
    const float* g1  = (const float*)d_in[6];
    const float* bt1 = (const float*)d_in[7];
    const float* W2  = (const float*)d_in[8];
    const float* b2  = (const float*)d_in[9];
    const float* g2  = (const float*)d_in[10];
    const float* bt2 = (const float*)d_in[11];
    const float* W3  = (const float*)d_in[12];
    const float* b3  = (const float*)d_in[13];

    int* outd = (int*)d_ws;
    int* ind  = outd + N_NODES;

    zero_i32<<<(2 * N_NODES + 255) / 256, 256, 0, stream>>>(outd, 2 * N_NODES);
    degree_hist<<<(NE + 255) / 256, 256, 0, stream>>>(src, dst, outd, ind);
    edge_mlp_mfma<<<512, 256, 0, stream>>>(emb, src, dst, noise,
                                           W1, b1, g1, bt1,
                                           W2, b2, g2, bt2,
                                           W3, b3, outd, ind,
                                           (float*)d_out);
}